// Round 13
// baseline (219.645 us; speedup 1.0000x reference)
//
#include <hip/hip_runtime.h>

// B=64, S=512, D=256, VOCAB=50000, NC=10, N_STEPS=10 (h=0.1), BN eval.
// z_final = z0 @ P10 + c10, P10 = M^10, M = Taylor4(exp(hA)), A = W^T.
// Transpose trick: M = N^T, N = I + B, B = 0.1W + 0.005W^2 + (1e-3/6)W^3 + (1e-4/24)W^4.
// Squared-binomial: D = N^2 - I = 2B + B^2; N^10 = sum C(5,k) D^k;
// ctot = V c1b, V = sum C(5,k+1) D^k, c1b = 2c1 + B c1.
//
// LESSONS (R1-R12):
//  - Intra-kernel global sync: 70-110us/event. Multi-dispatch only.
//  - 1024-thread blocks cap VGPR at 64 -> spills (R8/R9).
//  - R12: half-M tile doubled slab L2 traffic -> slower despite 2x occupancy.
//    Raise occupancy WITHOUT raising traffic: 512-thread blocks, M=64,
//    wave split mt=w&3 / ntq=w>>2 -> A-LDS traffic HALVES, B unchanged
//    (intra-block duplicates hit L1), 4 waves/SIMD. No setprio (R12 conf.).
//  - Prep: 512-thr K-split blocks (2 waves/SIMD, 2x64-load windows/pass).

typedef short bf16x8 __attribute__((ext_vector_type(8)));
typedef float f32x4 __attribute__((ext_vector_type(4)));

__device__ __forceinline__ unsigned short f2bf(float f) {
  unsigned u = __float_as_uint(f);
  u += 0x7FFFu + ((u >> 16) & 1u);   // RNE; inputs are normal floats
  return (unsigned short)(u >> 16);
}

// 512-thread row-GEMM pass: thread (c = t&255, g = t>>8) accumulates the
// K-half [g*128, g*128+128) in two 64-load register windows; LDS combine.
// Returns sum_k src[k]*Y[k][c] (valid for t < 256).
__device__ __forceinline__ float rpass512(const float* __restrict__ src,
                                          const float* __restrict__ Y,
                                          float* __restrict__ part,
                                          int c, int g, int t) {
  float a0 = 0.f, a1 = 0.f, a2 = 0.f, a3 = 0.f;
#pragma unroll 1
  for (int w2 = 0; w2 < 2; ++w2) {
    const int k0 = g * 128 + w2 * 64;
    float bv[64];
#pragma unroll
    for (int v = 0; v < 64; ++v) bv[v] = Y[(size_t)(k0 + v) * 256 + c];
#pragma unroll
    for (int v = 0; v < 64; v += 4) {
      a0 = fmaf(src[k0 + v + 0], bv[v + 0], a0);
      a1 = fmaf(src[k0 + v + 1], bv[v + 1], a1);
      a2 = fmaf(src[k0 + v + 2], bv[v + 2], a2);
      a3 = fmaf(src[k0 + v + 3], bv[v + 3], a3);
    }
  }
  part[t] = (a0 + a1) + (a2 + a3);
  __syncthreads();                       // also orders prior src reads
  return (t < 256) ? (part[t] + part[t + 256]) : 0.f;
}

// ---- d1: blocks 0-255: W-power row chain -> B row + c1[i].
//          blocks 256-447: conv repack (consecutive-kd lanes) + featbuf zero.
__global__ __launch_bounds__(512) void k_prep1(
    const float* __restrict__ W, const float* __restrict__ bode,
    const float* __restrict__ w3c, const float* __restrict__ w4c, const float* __restrict__ w5c,
    float* __restrict__ Bm, float* __restrict__ c1,
    unsigned short* __restrict__ slab, unsigned* __restrict__ featbuf) {
  __shared__ float part[512], r1[256], r2[256], r3[256], red[4];
  const int t = threadIdx.x, blk = blockIdx.x;
  const int c = t & 255, g = t >> 8;
  if (blk < 256) {
    const int i = blk;
    if (t < 256) r1[t] = W[i * 256 + t];
    __syncthreads();
    const float v2 = rpass512(r1, W, part, c, g, t);   // W^2[i][c]
    if (t < 256) r2[t] = v2;
    __syncthreads();
    const float v3 = rpass512(r2, W, part, c, g, t);   // W^3[i][c]
    if (t < 256) r3[t] = v3;
    __syncthreads();
    const float v4 = rpass512(r3, W, part, c, g, t);   // W^4[i][c]
    if (t < 256) {
      const float w1 = r1[t];
      Bm[i * 256 + t] = 0.1f * w1 + 0.005f * v2
                      + (0.001f / 6.f) * v3 + (0.0001f / 24.f) * v4;
      // c1[i] = 0.1*(b[i] + sum_k b[k]*(0.05 W[i,k] + (0.01/6) W2 + (0.001/24) W3))
      const float q = 0.05f * w1 + (0.01f / 6.f) * v2 + (0.001f / 24.f) * v3;
      float val = bode[t] * q;
#pragma unroll
      for (int off = 32; off > 0; off >>= 1) val += __shfl_down(val, off);
      if ((t & 63) == 0) red[t >> 6] = val;
    }
    __syncthreads();
    if (t == 0) c1[i] = 0.1f * (bode[i] + ((red[0] + red[1]) + (red[2] + red[3])));
  } else {
    const int base = (blk - 256) * 512 + t;     // 0..98303
#pragma unroll
    for (int u = 0; u < 4; ++u) {
      int e = base + u * 98304;                 // covers 0..393215 = 12*32768
      int s = e >> 15, r = e & 32767;
      int o = r >> 8, kd = r & 255;             // consecutive lane = consecutive kd
      const float* w; int k, j;
      if (s < 3)      { w = w3c; k = 3; j = s; }
      else if (s < 7) { w = w4c; k = 4; j = s - 3; }
      else            { w = w5c; k = 5; j = s - 7; }
      float val = w[(o * 256 + kd) * k + j];    // w[o][d=kd][j], shape (128,256,k)
      int kc = kd >> 5, quad = (kd >> 3) & 3, q8 = kd & 7;
      slab[s * 32768 + ((kc * 4 + quad) * 128 + o) * 8 + q8] = f2bf(val);
    }
    if (base < 64 * 640) featbuf[base] = 0u;
  }
}

// ---- d2a: block i: D[i] = 2B[i] + B^2[i]; c1b[i] = 2c1[i] + dot(B[i],c1).
__global__ __launch_bounds__(512) void k_prep2a(
    const float* __restrict__ Bm, const float* __restrict__ c1v,
    float* __restrict__ Dm, float* __restrict__ c1b) {
  __shared__ float part[512], r1[256], c1s[256], red[4];
  const int t = threadIdx.x, i = blockIdx.x;
  const int c = t & 255, g = t >> 8;
  if (t < 256) { r1[t] = Bm[i * 256 + t]; c1s[t] = c1v[t]; }
  __syncthreads();
  const float v2 = rpass512(r1, Bm, part, c, g, t);    // B^2[i][c]
  if (t < 256) {
    Dm[i * 256 + t] = 2.f * r1[t] + v2;
    float pd = r1[t] * c1s[t];
#pragma unroll
    for (int off = 32; off > 0; off >>= 1) pd += __shfl_down(pd, off);
    if ((t & 63) == 0) red[t >> 6] = pd;
  }
  __syncthreads();
  if (t == 0) c1b[i] = 2.f * c1s[i] + ((red[0] + red[1]) + (red[2] + red[3]));
}

// ---- d2b: block i: chain D[i] -> D^5[i] (4 passes, Y=D read-only).
// n10 = I + 5D + 10D^2 + 10D^3 + 5D^4 + D^5 -> slab node scatter.
// ct  = 5 c1b[i] + 10 dot(D,c1b) + 10 dot(D^2,c1b) + 5 dot(D^3,c1b) + dot(D^4,c1b).
__global__ __launch_bounds__(512) void k_prep2b(
    const float* __restrict__ Dm, const float* __restrict__ c1bv,
    float* __restrict__ c10, unsigned short* __restrict__ slab) {
  __shared__ float part[512], curs[256], cbs[256], red[4];
  const int t = threadIdx.x, i = blockIdx.x;
  const int c = t & 255, g = t >> 8;
  const float coefN[6] = {1.f, 5.f, 10.f, 10.f, 5.f, 1.f};   // C(5,k)
  const float coefC[5] = {5.f, 10.f, 10.f, 5.f, 1.f};        // C(5,k+1)
  float v = 0.f, n10 = 0.f, ct = 0.f;
  if (t < 256) {
    v = Dm[i * 256 + t];
    curs[t] = v;
    cbs[t] = c1bv[t];
  }
  __syncthreads();
  if (t < 256) {
    n10 = ((i == t) ? 1.f : 0.f) + coefN[1] * v;
    float pd = v * cbs[t];
#pragma unroll
    for (int off = 32; off > 0; off >>= 1) pd += __shfl_down(pd, off);
    if ((t & 63) == 0) red[t >> 6] = pd;
  }
  __syncthreads();
  if (t < 256) ct = coefC[0] * cbs[i] + coefC[1] * ((red[0] + red[1]) + (red[2] + red[3]));

#pragma unroll 1
  for (int k = 2; k <= 5; ++k) {
    v = rpass512(curs, Dm, part, c, g, t);   // D^k[i][c]; internal sync orders curs reads
    if (t < 256) {
      curs[t] = v;
      n10 = fmaf(coefN[k], v, n10);
      float pdk = v * cbs[t];
#pragma unroll
      for (int off = 32; off > 0; off >>= 1) pdk += __shfl_down(pdk, off);
      if ((t & 63) == 0) red[t >> 6] = pdk;
    }
    __syncthreads();                         // red + curs visible; part reads done
    if (t < 256 && k <= 4)
      ct = fmaf(coefC[k], (red[0] + red[1]) + (red[2] + red[3]), ct);
  }

  if (t < 256) {
    // scatter n10: element (kd=t, o=i) of the node B-matrix (P10[kd][o]=N10[o][kd])
    const int o = i, kd = t;
    const int kc = kd >> 5, quad = (kd >> 3) & 3, q8 = kd & 7;
    slab[(12 + (o >> 7)) * 32768 + ((kc * 4 + quad) * 128 + (o & 127)) * 8 + q8] = f2bf(n10);
  }
  if (t == 0) c10[i] = ct;
}

// ---------------- fused main kernel ----------------
// grid 512 = 64 batches x 8 t-chunks of 64 (R10 map). 512 threads = 8 waves.
// Wave split: mt = w&3 (16-row band), ntq = w>>2 (4 nt slots each).
// -> A-LDS traffic HALVED vs R10 (each A-frag read by 2 waves, not 4);
//    distinct B-frags per block unchanged (intra-block dups are L1 hits);
//    2 blocks/CU x 8 waves = 4 waves/SIMD. Depth-2 B pipeline, no barriers.

__global__ __launch_bounds__(512, 4) void k_main(
    const int* __restrict__ ids, const float* __restrict__ emb,
    const unsigned short* __restrict__ slab, const float* __restrict__ ctot,
    const float* __restrict__ b3, const float* __restrict__ g3, const float* __restrict__ be3,
    const float* __restrict__ b4, const float* __restrict__ g4, const float* __restrict__ be4,
    const float* __restrict__ b5, const float* __restrict__ g5, const float* __restrict__ be5,
    unsigned* __restrict__ featbuf) {
  __shared__ alignas(16) unsigned short Xt[68 * 264];
  __shared__ int ids_s[68];
  const int tid = threadIdx.x;
  const int blk = blockIdx.x;
  const int b = blk >> 3;
  const int t0 = (blk & 7) * 64;
  const int lane = tid & 63;
  const int wave = tid >> 6;       // 0..7
  const int m15 = lane & 15;
  const int quad = lane >> 4;
  const int mtw = wave & 3;        // row band: rows t0 + mtw*16 + quad*4 + r
  const int ntq = wave >> 2;       // nt slots ntq*4 .. ntq*4+3

  if (tid < 68) {
    int t = t0 + tid;
    ids_s[tid] = (t < 512) ? ids[b * 512 + t] : -1;
  }
  __syncthreads();

  // per-lane B-fragment base; frag(e,kc2,ntl) = fb0 + e*8192 + kc2*4096 + ntl*128
  const unsigned short* fb0 = slab + (size_t)quad * 1024 + ntq * 512 + m15 * 8;
  bf16x8 fA[8], fB[8];   // [kc2*4 + ntl], depth-2 entry pipeline
#define LDFRAG(DST, EN)                                                         \
  {                                                                             \
    const unsigned short* p_ = fb0 + (size_t)(EN) * 8192;                       \
    _Pragma("unroll")                                                           \
    for (int q = 0; q < 8; ++q)                                                 \
      DST[q] = *(const bf16x8*)(p_ + (q >> 2) * 4096 + (q & 3) * 128);          \
  }
  LDFRAG(fA, 0) LDFRAG(fB, 1)

  // gather + fp32->bf16 X tile (overlaps the frag loads above)
  for (int i = tid; i < 68 * 64; i += 512) {
    int row = i >> 6, s4 = i & 63;
    uint2 v = make_uint2(0u, 0u);
    int id = ids_s[row];
    if (id >= 0) {
      const float4 f = *(const float4*)(emb + (size_t)id * 256 + s4 * 4);
      v.x = (unsigned)f2bf(f.x) | ((unsigned)f2bf(f.y) << 16);
      v.y = (unsigned)f2bf(f.z) | ((unsigned)f2bf(f.w) << 16);
    }
    *(uint2*)&Xt[row * 264 + s4 * 4] = v;
  }
  __syncthreads();  // Xt ready; no further barriers

  f32x4 acc[4];
#pragma unroll
  for (int ntl = 0; ntl < 4; ++ntl) acc[ntl] = (f32x4){0.f, 0.f, 0.f, 0.f};

#define ENTRY(KCQ, FR)                                                          \
  {                                                                             \
    _Pragma("unroll")                                                           \
    for (int kc2 = 0; kc2 < 2; ++kc2) {                                         \
      const int kd0 = ((KCQ) * 2 + kc2) * 32 + quad * 8;                        \
      const bf16x8 af = *(const bf16x8*)&Xt[(shift + mtw * 16 + m15) * 264 + kd0]; \
      _Pragma("unroll")                                                         \
      for (int ntl = 0; ntl < 4; ++ntl)                                         \
        acc[ntl] = __builtin_amdgcn_mfma_f32_16x16x32_bf16(af, FR[kc2 * 4 + ntl], acc[ntl], 0, 0, 0); \
    }                                                                           \
  }

  for (int ep = 0; ep < 28; ++ep) {
    const int e0 = ep * 2;
    const int slice = e0 >> 2;             // e0,e0+1 share slice (e0 even)
    const int shift = (slice < 3) ? slice
                    : (slice < 7) ? (slice - 3)
                    : (slice < 12) ? (slice - 7) : 0;
    const int kcq0 = e0 & 3;

    ENTRY(kcq0, fA);
    if (ep < 27) LDFRAG(fA, e0 + 2)
    ENTRY(kcq0 + 1, fB);
    if (ep < 27) LDFRAG(fB, e0 + 3)

    // epilogue at group boundaries: ep 5 (conv3), 13 (conv4), 23 (conv5),
    // 25 (node lo), 27 (node hi)
    const int g = (ep == 5) ? 0 : (ep == 13) ? 1 : (ep == 23) ? 2
                : (ep == 25) ? 3 : (ep == 27) ? 4 : -1;
    if (g >= 0) {
      if (g < 3) {
        const int kk = g + 3;
        const float* bb  = (g == 0) ? b3 : (g == 1) ? b4 : b5;
        const float* gg  = (g == 0) ? g3 : (g == 1) ? g4 : g5;
        const float* bbe = (g == 0) ? be3 : (g == 1) ? be4 : be5;
        const int off = 256 + g * 128;     // feats: [node 256][p3 128][p4 128][p5 128]
        const int tmax = 512 - kk;
#pragma unroll
        for (int ntl = 0; ntl < 4; ++ntl) {
          const int n = (ntq * 4 + ntl) * 16 + m15;
          const float sc = gg[n] * 0.9999950000375f;  // g * 1/sqrt(1+1e-5)
          const float sh = fmaf(sc, bb[n], bbe[n]);
          float mx = 0.f;  // relu floor doubles as init
#pragma unroll
          for (int r = 0; r < 4; ++r) {
            const int t = t0 + mtw * 16 + quad * 4 + r;
            const float v = fmaf(sc, acc[ntl][r], sh);
            if (t <= tmax) mx = fmaxf(mx, v);
          }
          mx = fmaxf(mx, __shfl_xor(mx, 16));
          mx = fmaxf(mx, __shfl_xor(mx, 32));
          if (quad == 0) atomicMax(&featbuf[b * 640 + off + n], __float_as_uint(mx));
        }
      } else {
        const int base = (g == 3) ? 0 : 128;
#pragma unroll
        for (int ntl = 0; ntl < 4; ++ntl) {
          const int n = (ntq * 4 + ntl) * 16 + m15;
          const float ct = ctot[base + n];
          float mx = -3.4e38f;
#pragma unroll
          for (int r = 0; r < 4; ++r)
            mx = fmaxf(mx, acc[ntl][r] + ct);
          mx = fmaxf(mx, __shfl_xor(mx, 16));
          mx = fmaxf(mx, __shfl_xor(mx, 32));
          if (quad == 0) {
            unsigned bits = __float_as_uint(mx);
            unsigned key = (bits & 0x80000000u) ? ~bits : (bits | 0x80000000u);  // order-preserving
            atomicMax(&featbuf[b * 640 + base + n], key);
          }
        }
      }
      // reset accumulators for the next group
#pragma unroll
      for (int ntl = 0; ntl < 4; ++ntl) acc[ntl] = (f32x4){0.f, 0.f, 0.f, 0.f};
    }
  }
#undef ENTRY
#undef LDFRAG
}

// ---------------- classifier ----------------
__global__ void k_fin(const unsigned* __restrict__ featbuf, const float* __restrict__ wc,
                      const float* __restrict__ bc, float* __restrict__ out) {
  int b = blockIdx.x, lane = threadIdx.x;  // 64 threads = 1 wave
  float p[10];
#pragma unroll
  for (int c = 0; c < 10; ++c) p[c] = 0.f;
  for (int f = lane; f < 640; f += 64) {
    unsigned u = featbuf[b * 640 + f];
    float v;
    if (f < 256) v = (u & 0x80000000u) ? __uint_as_float(u ^ 0x80000000u) : __uint_as_float(~u);
    else v = __uint_as_float(u);
#pragma unroll
    for (int c = 0; c < 10; ++c) p[c] = fmaf(v, wc[c * 640 + f], p[c]);
  }
#pragma unroll
  for (int c = 0; c < 10; ++c) {
    float s = p[c];
#pragma unroll
    for (int off = 32; off > 0; off >>= 1) s += __shfl_down(s, off);
    if (lane == 0) out[b * 10 + c] = s + bc[c];
  }
}

// ---------------- launcher ----------------
extern "C" void kernel_launch(void* const* d_in, const int* in_sizes, int n_in,
                              void* d_out, int out_size, void* d_ws, size_t ws_size,
                              hipStream_t stream) {
  (void)in_sizes; (void)n_in; (void)out_size; (void)ws_size;
  const int*   ids  = (const int*)d_in[0];
  const float* emb  = (const float*)d_in[1];
  const float* W    = (const float*)d_in[2];
  const float* bode = (const float*)d_in[3];
  const float* w3   = (const float*)d_in[4];
  const float* b3   = (const float*)d_in[5];
  const float* g3   = (const float*)d_in[6];
  const float* be3  = (const float*)d_in[7];
  const float* w4   = (const float*)d_in[8];
  const float* b4   = (const float*)d_in[9];
  const float* g4   = (const float*)d_in[10];
  const float* be4  = (const float*)d_in[11];
  const float* w5   = (const float*)d_in[12];
  const float* b5   = (const float*)d_in[13];
  const float* g5   = (const float*)d_in[14];
  const float* be5  = (const float*)d_in[15];
  const float* wc   = (const float*)d_in[16];
  const float* bc   = (const float*)d_in[17];
  float* out = (float*)d_out;

  float* wsf = (float*)d_ws;
  // ws layout (floats): Bm 0 | Dm 65536 | c1 131072 | c1b 131328 | c10 131584 |
  // slab 131840 (14*32768 bf16 = 229376 floats) | featbuf 361216 (40960 uints)
  float* Bm  = wsf;
  float* Dm  = wsf + 65536;
  float* c1  = wsf + 131072;
  float* c1b = wsf + 131328;
  float* c10 = wsf + 131584;
  unsigned short* slab = (unsigned short*)(wsf + 131840);
  unsigned* featbuf = (unsigned*)(wsf + 361216);

  hipLaunchKernelGGL(k_prep1, dim3(448), dim3(512), 0, stream,
                     W, bode, w3, w4, w5, Bm, c1, slab, featbuf);
  hipLaunchKernelGGL(k_prep2a, dim3(256), dim3(512), 0, stream, Bm, c1, Dm, c1b);
  hipLaunchKernelGGL(k_prep2b, dim3(256), dim3(512), 0, stream, Dm, c1b, c10, slab);
  hipLaunchKernelGGL(k_main, dim3(512), dim3(512), 0, stream,
                     ids, emb, slab, c10,
                     b3, g3, be3, b4, g4, be4, b5, g5, be5, featbuf);
  hipLaunchKernelGGL(k_fin, dim3(64), dim3(64), 0, stream, featbuf, wc, bc, out);
}

// Round 14
// 188.460 us; speedup vs baseline: 1.1655x; 1.1655x over previous
//
#include <hip/hip_runtime.h>

// B=64, S=512, D=256, VOCAB=50000, NC=10, N_STEPS=10 (h=0.1), BN eval.
// z_final = z0 @ P10 + c10, P10 = M^10, M = Taylor4(exp(hA)), A = W^T.
// Transpose trick: M = N^T, N = I + B, B = 0.1W + 0.005W^2 + (1e-3/6)W^3 + (1e-4/24)W^4.
// Squared-binomial: D = N^2 - I = 2B + B^2; N^10 = sum C(5,k) D^k;
// ctot = V c1b, V = sum C(5,k+1) D^k, c1b = 2c1 + B c1.
//
// LESSONS (R1-R13):
//  - Intra-kernel global sync costs 70-110us/event ONLY when consumers poll
//    before the producer signals (contention at the coherence point). A gate
//    that is ALREADY SATISFIED when checked costs ~1us (one acquire load).
//  - Register spills are the repeat killer: 1024-thr blocks (cap 64, R8/R9),
//    8-wave k_main with launch_bounds(512,4) (R13: WRITE_SIZE 4x = scratch).
//    R10's k_main (256 thr, depth-2, VGPR 60) is the proven local optimum.
//  - Dispatch boundaries ~2us; prep BODIES (~9us/serial pass) dominate.
//  - THIS ROUND: prep2b (4 passes, ~35-45us) folded into k_main as blocks
//    0-255 (prep-first order), grid 768; main blocks gate at ep23 (~40us in,
//    prep done ~20us earlier -> no-wait). Capacity proof: launch_bounds(256,4)
//    VGPR<=128 + LDS 36KB -> 4 blocks/CU -> 1024 slots >= 768 (no deadlock).
//    Producer writes: agent-scope atomic stores + release-add (R7-proven).

typedef short bf16x8 __attribute__((ext_vector_type(8)));
typedef float f32x4 __attribute__((ext_vector_type(4)));

__device__ __forceinline__ unsigned short f2bf(float f) {
  unsigned u = __float_as_uint(f);
  u += 0x7FFFu + ((u >> 16) & 1u);   // RNE; inputs are normal floats
  return (unsigned short)(u >> 16);
}

// agent-scope (coherence-point) stores — R7-proven producer path
__device__ __forceinline__ void gstf(float* p, float v) {
  __hip_atomic_store(p, v, __ATOMIC_RELAXED, __HIP_MEMORY_SCOPE_AGENT);
}
__device__ __forceinline__ void gst16(unsigned short* p, unsigned short v) {
  __hip_atomic_store(p, v, __ATOMIC_RELAXED, __HIP_MEMORY_SCOPE_AGENT);
}

// acc = sum_k xrow[k] * Y[k][c]; xrow in LDS, Y global row-major, coalesced
// across c. Windows of 64 loads fully in VGPRs (256-thread blocks only!).
__device__ __forceinline__ float dotcol64(const float* __restrict__ xrow,
                                          const float* __restrict__ Y, int c) {
  float a0 = 0.f, a1 = 0.f, a2 = 0.f, a3 = 0.f;
#pragma unroll 1
  for (int w = 0; w < 4; ++w) {
    float bv[64];
#pragma unroll
    for (int v = 0; v < 64; ++v) bv[v] = Y[(w * 64 + v) * 256 + c];
#pragma unroll
    for (int v = 0; v < 64; v += 4) {
      a0 = fmaf(xrow[w * 64 + v + 0], bv[v + 0], a0);
      a1 = fmaf(xrow[w * 64 + v + 1], bv[v + 1], a1);
      a2 = fmaf(xrow[w * 64 + v + 2], bv[v + 2], a2);
      a3 = fmaf(xrow[w * 64 + v + 3], bv[v + 3], a3);
    }
  }
  return (a0 + a1) + (a2 + a3);
}

// ---- d1: blocks 0-255: W-power row chain -> B row + c1[i].
//          blocks 256-639: conv repack (consecutive-kd lanes) + featbuf/cnt zero.
__global__ __launch_bounds__(256) void k_prep1(
    const float* __restrict__ W, const float* __restrict__ bode,
    const float* __restrict__ w3c, const float* __restrict__ w4c, const float* __restrict__ w5c,
    float* __restrict__ Bm, float* __restrict__ c1,
    unsigned short* __restrict__ slab, unsigned* __restrict__ featbuf) {
  __shared__ float r1[256], r2[256], r3[256], red[4];
  const int tid = threadIdx.x, blk = blockIdx.x;
  if (blk < 256) {
    const int i = blk;
    r1[tid] = W[i * 256 + tid];
    __syncthreads();
    const float v2 = dotcol64(r1, W, tid);   // W^2[i][tid]
    r2[tid] = v2;
    __syncthreads();
    const float v3 = dotcol64(r2, W, tid);   // W^3[i][tid]
    r3[tid] = v3;
    __syncthreads();
    const float v4 = dotcol64(r3, W, tid);   // W^4[i][tid]
    const float w1 = r1[tid];
    Bm[i * 256 + tid] = 0.1f * w1 + 0.005f * v2
                      + (0.001f / 6.f) * v3 + (0.0001f / 24.f) * v4;
    // c1[i] = 0.1*(b[i] + sum_k b[k]*(0.05 W[i,k] + (0.01/6) W2[i,k] + (0.001/24) W3[i,k]))
    const float q = 0.05f * w1 + (0.01f / 6.f) * v2 + (0.001f / 24.f) * v3;
    float val = bode[tid] * q;
#pragma unroll
    for (int off = 32; off > 0; off >>= 1) val += __shfl_down(val, off);
    if ((tid & 63) == 0) red[tid >> 6] = val;
    __syncthreads();
    if (tid == 0) c1[i] = 0.1f * (bode[i] + ((red[0] + red[1]) + (red[2] + red[3])));
  } else {
    const int base = (blk - 256) * 256 + tid;   // 0..98303
#pragma unroll
    for (int u = 0; u < 4; ++u) {
      int e = base + u * 98304;                 // covers 0..393215 = 12*32768
      int s = e >> 15, r = e & 32767;
      int o = r >> 8, kd = r & 255;             // consecutive lane = consecutive kd
      const float* w; int k, j;
      if (s < 3)      { w = w3c; k = 3; j = s; }
      else if (s < 7) { w = w4c; k = 4; j = s - 3; }
      else            { w = w5c; k = 5; j = s - 7; }
      float val = w[(o * 256 + kd) * k + j];    // w[o][d=kd][j], shape (128,256,k)
      int kc = kd >> 5, quad = (kd >> 3) & 3, q8 = kd & 7;
      slab[s * 32768 + ((kc * 4 + quad) * 128 + o) * 8 + q8] = f2bf(val);
    }
    if (base <= 64 * 640) featbuf[base] = 0u;   // includes nodecnt at [40960]
  }
}

// ---- d2a: block i: D[i] = 2B[i] + B^2[i]; c1b[i] = 2c1[i] + dot(B[i],c1).
__global__ __launch_bounds__(256) void k_prep2a(
    const float* __restrict__ Bm, const float* __restrict__ c1v,
    float* __restrict__ Dm, float* __restrict__ c1b) {
  __shared__ float r1[256], c1s[256], red[4];
  const int tid = threadIdx.x, i = blockIdx.x;
  r1[tid] = Bm[i * 256 + tid];
  c1s[tid] = c1v[tid];
  __syncthreads();
  const float v2 = dotcol64(r1, Bm, tid);      // B^2[i][tid]
  Dm[i * 256 + tid] = 2.f * r1[tid] + v2;
  float pd = r1[tid] * c1s[tid];
#pragma unroll
  for (int off = 32; off > 0; off >>= 1) pd += __shfl_down(pd, off);
  if ((tid & 63) == 0) red[tid >> 6] = pd;
  __syncthreads();
  if (tid == 0) c1b[i] = 2.f * c1s[i] + ((red[0] + red[1]) + (red[2] + red[3]));
}

// ---------------- fused main kernel: prep2b (blocks 0-255) + GEMM (256-767) ----
// prep2b: chain D[i]->D^5[i] (4 passes, Y=D read-only), n10 = sum C(5,k)D^k ->
//   slab node scatter (agent stores); ct -> c10; release-add nodecnt; EXIT.
// main: R10-proven body (M=64, 4 waves, depth-2 B pipeline, no loop barriers);
//   gate on nodecnt at ep23, just before node-entry prefetch (satisfied by then).
// Capacity: launch_bounds(256,4) VGPR<=128 + 36KB LDS -> 4 blocks/CU -> all
// 768 blocks co-resident regardless of dispatch order (no deadlock).

__global__ __launch_bounds__(256, 4) void k_main(
    const int* __restrict__ ids, const float* __restrict__ emb,
    unsigned short* __restrict__ slab, const float* __restrict__ Dm,
    const float* __restrict__ c1bv, float* __restrict__ c10,
    const float* __restrict__ b3, const float* __restrict__ g3, const float* __restrict__ be3,
    const float* __restrict__ b4, const float* __restrict__ g4, const float* __restrict__ be4,
    const float* __restrict__ b5, const float* __restrict__ g5, const float* __restrict__ be5,
    unsigned* __restrict__ featbuf) {
  __shared__ alignas(16) unsigned short Xt[68 * 264];
  __shared__ int ids_s[68];
  const int tid = threadIdx.x;
  const int blk = blockIdx.x;
  unsigned* nodecnt = featbuf + 64 * 640;

  if (blk < 256) {
    // ---------------- prep2b path (LDS aliased onto Xt) ----------------
    float* curs = (float*)Xt;          // 256 floats
    float* cbs  = curs + 256;
    float* redp = curs + 512;          // 4 floats
    const int i = blk;
    const float coefN[6] = {1.f, 5.f, 10.f, 10.f, 5.f, 1.f};   // C(5,k)
    const float coefC[5] = {5.f, 10.f, 10.f, 5.f, 1.f};        // C(5,k+1)
    float v = Dm[i * 256 + tid];
    curs[tid] = v;
    cbs[tid] = c1bv[tid];
    __syncthreads();
    float n10 = ((i == tid) ? 1.f : 0.f) + coefN[1] * v;
    float pd = v * cbs[tid];
#pragma unroll
    for (int off = 32; off > 0; off >>= 1) pd += __shfl_down(pd, off);
    if ((tid & 63) == 0) redp[tid >> 6] = pd;
    __syncthreads();
    float ct = coefC[0] * cbs[i] + coefC[1] * ((redp[0] + redp[1]) + (redp[2] + redp[3]));

#pragma unroll 1
    for (int k = 2; k <= 5; ++k) {
      v = dotcol64(curs, Dm, tid);      // D^k[i][tid]
      __syncthreads();                  // all reads of curs done
      curs[tid] = v;
      n10 = fmaf(coefN[k], v, n10);
      float pdk = v * cbs[tid];
#pragma unroll
      for (int off = 32; off > 0; off >>= 1) pdk += __shfl_down(pdk, off);
      if ((tid & 63) == 0) redp[tid >> 6] = pdk;
      __syncthreads();                  // redp ready; curs visible
      if (k <= 4) ct = fmaf(coefC[k], (redp[0] + redp[1]) + (redp[2] + redp[3]), ct);
    }

    // scatter n10: element (kd=tid, o=i) of node B-matrix (P10[kd][o]=N10[o][kd])
    {
      const int o = i, kd = tid;
      const int kc = kd >> 5, quad = (kd >> 3) & 3, q8 = kd & 7;
      gst16(&slab[(12 + (o >> 7)) * 32768 + ((kc * 4 + quad) * 128 + (o & 127)) * 8 + q8],
            f2bf(n10));
    }
    if (tid == 0) gstf(&c10[i], ct);
    __syncthreads();                    // all stores issued (per-thread ordering to atomic below)
    if (tid == 0)
      __hip_atomic_fetch_add(nodecnt, 1u, __ATOMIC_RELEASE, __HIP_MEMORY_SCOPE_AGENT);
    return;
  }

  // ---------------- main GEMM path (R10-proven body) ----------------
  const int mb = blk - 256;
  const int b = mb >> 3;
  const int t0 = (mb & 7) * 64;
  const int lane = tid & 63;
  const int wave = tid >> 6;
  const int m15 = lane & 15;
  const int quad = lane >> 4;

  if (tid < 68) {
    int t = t0 + tid;
    ids_s[tid] = (t < 512) ? ids[b * 512 + t] : -1;
  }
  __syncthreads();
  // gather + fp32->bf16 X tile (rows beyond S zero-filled)
  for (int i = tid; i < 68 * 64; i += 256) {
    int row = i >> 6, s4 = i & 63;
    uint2 v = make_uint2(0u, 0u);
    int id = ids_s[row];
    if (id >= 0) {
      const float4 f = *(const float4*)(emb + (size_t)id * 256 + s4 * 4);
      v.x = (unsigned)f2bf(f.x) | ((unsigned)f2bf(f.y) << 16);
      v.y = (unsigned)f2bf(f.z) | ((unsigned)f2bf(f.w) << 16);
    }
    *(uint2*)&Xt[row * 264 + s4 * 4] = v;
  }
  __syncthreads();  // Xt ready; no further block barriers in the loop

  // per-lane B-fragment bases (bf16 units); frag(e,kc2,nt) = fb[nt] + e*8192 + kc2*4096
  const unsigned short* fb0 = slab + ((size_t)quad * 128 + (wave * 2 + 0) * 16 + m15) * 8;
  const unsigned short* fb1 = fb0 + 128;   // nt=1: +16*8

  bf16x8 fA[4], fB[4];   // [kc2*2+nt]
#pragma unroll
  for (int q = 0; q < 4; ++q) {
    fA[q] = *(const bf16x8*)(((q & 1) ? fb1 : fb0) + (q >> 1) * 4096);
    fB[q] = *(const bf16x8*)(((q & 1) ? fb1 : fb0) + 8192 + (q >> 1) * 4096);
  }

  f32x4 acc[4][2];
#pragma unroll
  for (int mt = 0; mt < 4; ++mt)
#pragma unroll
    for (int nt = 0; nt < 2; ++nt) acc[mt][nt] = (f32x4){0.f, 0.f, 0.f, 0.f};

#define ENTRY(KCQ, FR)                                                          \
  {                                                                             \
    _Pragma("unroll")                                                           \
    for (int kc2 = 0; kc2 < 2; ++kc2) {                                         \
      const int kd0 = ((KCQ) * 2 + kc2) * 32 + quad * 8;                        \
      bf16x8 af[4];                                                             \
      _Pragma("unroll")                                                         \
      for (int mt = 0; mt < 4; ++mt)                                            \
        af[mt] = *(const bf16x8*)&Xt[(shift + mt * 16 + m15) * 264 + kd0];      \
      _Pragma("unroll")                                                         \
      for (int mt = 0; mt < 4; ++mt) {                                          \
        acc[mt][0] = __builtin_amdgcn_mfma_f32_16x16x32_bf16(af[mt], FR[kc2 * 2 + 0], acc[mt][0], 0, 0, 0); \
        acc[mt][1] = __builtin_amdgcn_mfma_f32_16x16x32_bf16(af[mt], FR[kc2 * 2 + 1], acc[mt][1], 0, 0, 0); \
      }                                                                         \
    }                                                                           \
  }

  for (int ep = 0; ep < 28; ++ep) {
    // gate before node-entry prefetch (entries 48,49 prefetched during ep23).
    // By now (~40us in) the 256 prep blocks (done ~20us) have signaled:
    // expected cost = one satisfied acquire load.
    if (ep == 23) {
      if (tid == 0) {
        while (__hip_atomic_load(nodecnt, __ATOMIC_ACQUIRE, __HIP_MEMORY_SCOPE_AGENT) < 256u)
          __builtin_amdgcn_s_sleep(8);
      }
      __syncthreads();
    }
    const int e0 = ep * 2;
    const int slice = e0 >> 2;             // e0,e0+1 share slice (e0 even)
    const int shift = (slice < 3) ? slice
                    : (slice < 7) ? (slice - 3)
                    : (slice < 12) ? (slice - 7) : 0;
    const int kcq0 = e0 & 3;

    ENTRY(kcq0, fA);
    if (ep < 27) {
      const int eo = (e0 + 2) * 8192;
#pragma unroll
      for (int q = 0; q < 4; ++q)
        fA[q] = *(const bf16x8*)(((q & 1) ? fb1 : fb0) + eo + (q >> 1) * 4096);
    }
    ENTRY(kcq0 + 1, fB);
    if (ep < 27) {
      const int eo = (e0 + 3) * 8192;
#pragma unroll
      for (int q = 0; q < 4; ++q)
        fB[q] = *(const bf16x8*)(((q & 1) ? fb1 : fb0) + eo + (q >> 1) * 4096);
    }

    // epilogue at group boundaries: ep 5 (conv3), 13 (conv4), 23 (conv5),
    // 25 (node lo), 27 (node hi)
    const int g = (ep == 5) ? 0 : (ep == 13) ? 1 : (ep == 23) ? 2
                : (ep == 25) ? 3 : (ep == 27) ? 4 : -1;
    if (g >= 0) {
      if (g < 3) {
        const int kk = g + 3;
        const float* bb  = (g == 0) ? b3 : (g == 1) ? b4 : b5;
        const float* gg  = (g == 0) ? g3 : (g == 1) ? g4 : g5;
        const float* bbe = (g == 0) ? be3 : (g == 1) ? be4 : be5;
        const int off = 256 + g * 128;     // feats: [node 256][p3 128][p4 128][p5 128]
        const int tmax = 512 - kk;
#pragma unroll
        for (int nt = 0; nt < 2; ++nt) {
          const int n = (wave * 2 + nt) * 16 + m15;
          const float sc = gg[n] * 0.9999950000375f;  // g * 1/sqrt(1+1e-5)
          const float sh = fmaf(sc, bb[n], bbe[n]);
          float mx = 0.f;  // relu floor doubles as init
#pragma unroll
          for (int mt = 0; mt < 4; ++mt)
#pragma unroll
            for (int r = 0; r < 4; ++r) {
              const int t = t0 + mt * 16 + quad * 4 + r;
              const float v = fmaf(sc, acc[mt][nt][r], sh);
              if (t <= tmax) mx = fmaxf(mx, v);
            }
          mx = fmaxf(mx, __shfl_xor(mx, 16));
          mx = fmaxf(mx, __shfl_xor(mx, 32));
          if (quad == 0) atomicMax(&featbuf[b * 640 + off + n], __float_as_uint(mx));
        }
      } else {
        const int base = (g == 3) ? 0 : 128;
#pragma unroll
        for (int nt = 0; nt < 2; ++nt) {
          const int n = (wave * 2 + nt) * 16 + m15;
          const float ct = c10[base + n];
          float mx = -3.4e38f;
#pragma unroll
          for (int mt = 0; mt < 4; ++mt)
#pragma unroll
            for (int r = 0; r < 4; ++r)
              mx = fmaxf(mx, acc[mt][nt][r] + ct);
          mx = fmaxf(mx, __shfl_xor(mx, 16));
          mx = fmaxf(mx, __shfl_xor(mx, 32));
          if (quad == 0) {
            unsigned bits = __float_as_uint(mx);
            unsigned key = (bits & 0x80000000u) ? ~bits : (bits | 0x80000000u);  // order-preserving
            atomicMax(&featbuf[b * 640 + base + n], key);
          }
        }
      }
      // reset accumulators for the next group
#pragma unroll
      for (int mt = 0; mt < 4; ++mt)
#pragma unroll
        for (int nt = 0; nt < 2; ++nt) acc[mt][nt] = (f32x4){0.f, 0.f, 0.f, 0.f};
    }
  }
#undef ENTRY
}

// ---------------- classifier ----------------
__global__ void k_fin(const unsigned* __restrict__ featbuf, const float* __restrict__ wc,
                      const float* __restrict__ bc, float* __restrict__ out) {
  int b = blockIdx.x, lane = threadIdx.x;  // 64 threads = 1 wave
  float p[10];
#pragma unroll
  for (int c = 0; c < 10; ++c) p[c] = 0.f;
  for (int f = lane; f < 640; f += 64) {
    unsigned u = featbuf[b * 640 + f];
    float v;
    if (f < 256) v = (u & 0x80000000u) ? __uint_as_float(u ^ 0x80000000u) : __uint_as_float(~u);
    else v = __uint_as_float(u);
#pragma unroll
    for (int c = 0; c < 10; ++c) p[c] = fmaf(v, wc[c * 640 + f], p[c]);
  }
#pragma unroll
  for (int c = 0; c < 10; ++c) {
    float s = p[c];
#pragma unroll
    for (int off = 32; off > 0; off >>= 1) s += __shfl_down(s, off);
    if (lane == 0) out[b * 10 + c] = s + bc[c];
  }
}

// ---------------- launcher ----------------
extern "C" void kernel_launch(void* const* d_in, const int* in_sizes, int n_in,
                              void* d_out, int out_size, void* d_ws, size_t ws_size,
                              hipStream_t stream) {
  (void)in_sizes; (void)n_in; (void)out_size; (void)ws_size;
  const int*   ids  = (const int*)d_in[0];
  const float* emb  = (const float*)d_in[1];
  const float* W    = (const float*)d_in[2];
  const float* bode = (const float*)d_in[3];
  const float* w3   = (const float*)d_in[4];
  const float* b3   = (const float*)d_in[5];
  const float* g3   = (const float*)d_in[6];
  const float* be3  = (const float*)d_in[7];
  const float* w4   = (const float*)d_in[8];
  const float* b4   = (const float*)d_in[9];
  const float* g4   = (const float*)d_in[10];
  const float* be4  = (const float*)d_in[11];
  const float* w5   = (const float*)d_in[12];
  const float* b5   = (const float*)d_in[13];
  const float* g5   = (const float*)d_in[14];
  const float* be5  = (const float*)d_in[15];
  const float* wc   = (const float*)d_in[16];
  const float* bc   = (const float*)d_in[17];
  float* out = (float*)d_out;

  float* wsf = (float*)d_ws;
  // ws layout (floats): Bm 0 | Dm 65536 | c1 131072 | c1b 131328 | c10 131584 |
  // slab 131840 (14*32768 bf16 = 229376 floats) | featbuf 361216 (40961 uints)
  float* Bm  = wsf;
  float* Dm  = wsf + 65536;
  float* c1  = wsf + 131072;
  float* c1b = wsf + 131328;
  float* c10 = wsf + 131584;
  unsigned short* slab = (unsigned short*)(wsf + 131840);
  unsigned* featbuf = (unsigned*)(wsf + 361216);

  hipLaunchKernelGGL(k_prep1, dim3(640), dim3(256), 0, stream,
                     W, bode, w3, w4, w5, Bm, c1, slab, featbuf);
  hipLaunchKernelGGL(k_prep2a, dim3(256), dim3(256), 0, stream, Bm, c1, Dm, c1b);
  hipLaunchKernelGGL(k_main, dim3(768), dim3(256), 0, stream,
                     ids, emb, slab, Dm, c1b, c10,
                     b3, g3, be3, b4, g4, be4, b5, g5, be5, featbuf);
  hipLaunchKernelGGL(k_fin, dim3(64), dim3(64), 0, stream, featbuf, wc, bc, out);
}